// Round 3
// baseline (273.875 us; speedup 1.0000x reference)
//
#include <hip/hip_runtime.h>
#include <math.h>

#define B 256
#define V 128000
#define VF4 (V / 4)            // 32000 float4 per row
#define NBLK 25                // blocks per row
#define BLKF4 (VF4 / NBLK)     // 1280 float4 per block
#define BLOCK 256              // 4 waves
#define UNROLL 5               // BLKF4 / BLOCK — float4 pairs per thread
#define NOISE_MIN 1e-10f

// monotone (order-preserving) float32 -> uint32 encoding
__device__ __forceinline__ unsigned int enc_f32(float f) {
    unsigned int b = __float_as_uint(f);
    return (b & 0x80000000u) ? ~b : (b | 0x80000000u);
}

// pack so that u64 max == (max value, then min index)
__device__ __forceinline__ unsigned long long pack(float v, int i) {
    return ((unsigned long long)enc_f32(v) << 32) |
           (unsigned int)(0x7FFFFFFF - i);
}

__device__ __forceinline__ void upd(float v, int i, float& bv, int& bi) {
    if (v > bv || (v == bv && i < bi)) { bv = v; bi = i; }
}

__global__ __launch_bounds__(BLOCK) void sampler_kernel(
    const float* __restrict__ logits,
    const float* __restrict__ temps,
    const float* __restrict__ noise,
    unsigned long long* __restrict__ ws)
{
    const int blk = blockIdx.x;        // 0..NBLK-1
    const int row = blockIdx.y;        // 0..B-1
    const float t = temps[row];
    const bool greedy = (t <= 0.0f);   // block-uniform
    const float invT = greedy ? 1.0f : (1.0f / t);

    const size_t base = (size_t)row * VF4 + (size_t)blk * BLKF4;
    const float4* __restrict__ lg = reinterpret_cast<const float4*>(logits) + base;
    const float4* __restrict__ nz = reinterpret_cast<const float4*>(noise)  + base;

    // ---- issue ALL loads up front: 5 (+5) independent dwordx4 per thread ----
    float4 l[UNROLL];
    #pragma unroll
    for (int j = 0; j < UNROLL; ++j)
        l[j] = lg[threadIdx.x + j * BLOCK];

    float4 n[UNROLL];
    if (!greedy) {
        #pragma unroll
        for (int j = 0; j < UNROLL; ++j)
            n[j] = nz[threadIdx.x + j * BLOCK];
    }

    float bestVal = -INFINITY;
    int   bestIdx = 0x7FFFFFFF;
    const int ibase = (int)(blk * BLKF4) + (int)threadIdx.x;

    if (greedy) {
        #pragma unroll
        for (int j = 0; j < UNROLL; ++j) {
            int i0 = (ibase + j * BLOCK) << 2;
            upd(l[j].x, i0 + 0, bestVal, bestIdx);
            upd(l[j].y, i0 + 1, bestVal, bestIdx);
            upd(l[j].z, i0 + 2, bestVal, bestIdx);
            upd(l[j].w, i0 + 3, bestVal, bestIdx);
        }
    } else {
        #pragma unroll
        for (int j = 0; j < UNROLL; ++j) {
            int i0 = (ibase + j * BLOCK) << 2;
            float kx = l[j].x * invT - __logf(fmaxf(n[j].x, NOISE_MIN));
            float ky = l[j].y * invT - __logf(fmaxf(n[j].y, NOISE_MIN));
            float kz = l[j].z * invT - __logf(fmaxf(n[j].z, NOISE_MIN));
            float kw = l[j].w * invT - __logf(fmaxf(n[j].w, NOISE_MIN));
            upd(kx, i0 + 0, bestVal, bestIdx);
            upd(ky, i0 + 1, bestVal, bestIdx);
            upd(kz, i0 + 2, bestVal, bestIdx);
            upd(kw, i0 + 3, bestVal, bestIdx);
        }
    }

    // wave (64-lane) butterfly max on packed key — == (max val, min idx)
    unsigned long long best = pack(bestVal, bestIdx);
    #pragma unroll
    for (int off = 32; off > 0; off >>= 1) {
        unsigned long long o = __shfl_down(best, off, 64);
        if (o > best) best = o;
    }

    if ((threadIdx.x & 63) == 0) {
        atomicMax(&ws[row], best);   // device-scope by default on CDNA
    }
}

__global__ void decode_kernel(const unsigned long long* __restrict__ ws,
                              int* __restrict__ out)
{
    int i = threadIdx.x;
    out[i] = 0x7FFFFFFF - (int)(ws[i] & 0xFFFFFFFFu);
}

extern "C" void kernel_launch(void* const* d_in, const int* in_sizes, int n_in,
                              void* d_out, int out_size, void* d_ws, size_t ws_size,
                              hipStream_t stream) {
    const float* logits = (const float*)d_in[0];   // [B, V] f32
    const float* temps  = (const float*)d_in[1];   // [B]    f32
    const float* noise  = (const float*)d_in[2];   // [B, V] f32
    int* out = (int*)d_out;                        // [B] int32
    unsigned long long* ws = (unsigned long long*)d_ws;

    // ws re-poisoned to 0xAA each call; 0 is below every packed key.
    hipMemsetAsync(ws, 0, B * sizeof(unsigned long long), stream);

    dim3 grid(NBLK, B);
    sampler_kernel<<<grid, BLOCK, 0, stream>>>(logits, temps, noise, ws);
    decode_kernel<<<1, B, 0, stream>>>(ws, out);
}